// Round 13
// baseline (113.057 us; speedup 1.0000x reference)
//
#include <hip/hip_runtime.h>

// y[b,h,l] = sum_{m<=l} x[b,h,m] k[h,l-m] + D[h] x[b,h,l]   (C = 1)
//
// Half-size real-FFT, 16^3 factorization, 5 LDS phases (r12 structure).
// r13 change: pad layout (34816 B, 4 blocks/CU) -> XOR swizzle
// SW(i)=i^((i>>4)&15) at exactly 32768 B -> 5 blocks/CU. Swizzle analysis
// for the three access patterns (all <=4-way on bank pairs):
//   P1/P5  i=t+256j : (i>>4)&15 = t>>4  -> addr=(t^(t>>4))+256j
//   P2/P4  i=base+16j: (i>>4)&15 = j    -> addr=baseU+16j+((t&15)^j)
//   P3     i=16t+j  : (i>>4)&15 = t&15  -> addr=16t+(j^(t&15))
//
// Everything else = r12 (passing): z[n]=x[2n]+i x[2n+1]; FFT_4096 via 3
// radix-16 register passes; V[p]=G1[p]Z[p]+G2[p]conj(Z[partner]); IFFT;
// y from Re/Im; per-position G from kspec -> d_ws (64 MB); k=0 folded into
// G; a=0 self-pair via compile-time involution table.
#define Bdim 4
#define Hdim 1024
#define Ldim 4096
#define NH   4096
#define NTHR 256
#define R2C  0.70710678118654752440f
#define C16C 0.92387953251128675613f
#define S16C 0.38268343236508977173f
#define INVM (1.0f / 8192.0f)

__device__ __forceinline__ int SW3(int i) { return i ^ ((i >> 4) & 15); }
__device__ __forceinline__ int bitrev12(int k) { return (int)(__brev((unsigned)k) >> 20); }
__device__ __forceinline__ int bitrev8(int k)  { return (int)(__brev((unsigned)k) >> 24); }

__device__ __forceinline__ void sincos_rev(float f, float& s, float& c) {
#if __has_builtin(__builtin_amdgcn_sinf) && __has_builtin(__builtin_amdgcn_cosf)
    s = __builtin_amdgcn_sinf(f);
    c = __builtin_amdgcn_cosf(f);
#else
    __sincosf(f * 6.28318530717958647692f, &s, &c);
#endif
}

__device__ __forceinline__ float2 cadd(float2 a, float2 b) { return make_float2(a.x + b.x, a.y + b.y); }
__device__ __forceinline__ float2 csub(float2 a, float2 b) { return make_float2(a.x - b.x, a.y - b.y); }
__device__ __forceinline__ float2 cmul(float2 a, float2 b) {
    return make_float2(a.x * b.x - a.y * b.y, a.x * b.y + a.y * b.x);
}
__device__ __forceinline__ float2 mulc(float2 a, float cr, float ci) {
    return make_float2(a.x * cr - a.y * ci, a.x * ci + a.y * cr);
}
__device__ __forceinline__ float2 cmuli(float2 a)    { return make_float2(-a.y, a.x); }
__device__ __forceinline__ float2 cmulnegi(float2 a) { return make_float2(a.y, -a.x); }
__device__ __forceinline__ float2 conjf(float2 a)    { return make_float2(a.x, -a.y); }

#define FBF(i, jj, tw)      { float2 u_ = e[i]; float2 d_ = csub(u_, e[jj]); e[i] = cadd(u_, e[jj]); e[jj] = cmul(d_, tw); }
#define FBFC(i, jj, cr, ci) { float2 u_ = e[i]; float2 d_ = csub(u_, e[jj]); e[i] = cadd(u_, e[jj]); e[jj] = mulc(d_, cr, ci); }
#define FBFN(i, jj)         { float2 u_ = e[i]; float2 d_ = csub(u_, e[jj]); e[i] = cadd(u_, e[jj]); e[jj] = cmulnegi(d_); }
#define BFU(i, jj)          { float2 u_ = e[i]; float2 v_ = e[jj]; e[i] = cadd(u_, v_); e[jj] = csub(u_, v_); }
#define IBF(i, jj, tw)      { float2 tv_ = cmul(e[jj], tw); float2 u_ = e[i]; e[i] = cadd(u_, tv_); e[jj] = csub(u_, tv_); }
#define IBFC(i, jj, cr, ci) { float2 tv_ = mulc(e[jj], cr, ci); float2 u_ = e[i]; e[i] = cadd(u_, tv_); e[jj] = csub(u_, tv_); }
#define IBFI(i, jj)         { float2 tv_ = cmuli(e[jj]); float2 u_ = e[i]; e[i] = cadd(u_, tv_); e[jj] = csub(u_, tv_); }

__device__ __forceinline__ void fwd16_tail(float2 e[16], float2 w) {
    float2 w2 = cmul(w, w);
    float2 u1 = mulc(w2, R2C, -R2C);
    float2 u2 = cmulnegi(w2);
    float2 u3 = cmulnegi(u1);
    FBF(0,4,w2) FBF(1,5,u1) FBF(2,6,u2) FBF(3,7,u3)
    FBF(8,12,w2) FBF(9,13,u1) FBF(10,14,u2) FBF(11,15,u3)
    float2 w4 = cmul(w2, w2);
    float2 w4n = cmulnegi(w4);
    FBF(0,2,w4) FBF(1,3,w4n) FBF(4,6,w4) FBF(5,7,w4n)
    FBF(8,10,w4) FBF(9,11,w4n) FBF(12,14,w4) FBF(13,15,w4n)
    float2 w8 = cmul(w4, w4);
    FBF(0,1,w8) FBF(2,3,w8) FBF(4,5,w8) FBF(6,7,w8)
    FBF(8,9,w8) FBF(10,11,w8) FBF(12,13,w8) FBF(14,15,w8)
}
__device__ __forceinline__ void fwd16(float2 e[16], float2 w) {
    float2 t1 = mulc(w, C16C, -S16C);
    float2 t2 = mulc(w, R2C, -R2C);
    float2 t3 = mulc(w, S16C, -C16C);
    float2 t4 = cmulnegi(w);
    float2 t5 = cmulnegi(t1);
    float2 t6 = cmulnegi(t2);
    float2 t7 = cmulnegi(t3);
    FBF(0,8,w) FBF(1,9,t1) FBF(2,10,t2) FBF(3,11,t3)
    FBF(4,12,t4) FBF(5,13,t5) FBF(6,14,t6) FBF(7,15,t7)
    fwd16_tail(e, w);
}
__device__ __forceinline__ void fwd16_zero(float2 e[16], float2 w) {
    float2 t1 = mulc(w, C16C, -S16C);
    float2 t2 = mulc(w, R2C, -R2C);
    float2 t3 = mulc(w, S16C, -C16C);
    e[8]  = cmul(e[0], w);
    e[9]  = cmul(e[1], t1);
    e[10] = cmul(e[2], t2);
    e[11] = cmul(e[3], t3);
    e[12] = cmul(e[4], cmulnegi(w));
    e[13] = cmul(e[5], cmulnegi(t1));
    e[14] = cmul(e[6], cmulnegi(t2));
    e[15] = cmul(e[7], cmulnegi(t3));
    fwd16_tail(e, w);
}
__device__ __forceinline__ void fwd16_unit(float2 e[16]) {
    BFU(0,8)
    FBFC(1,9,   C16C, -S16C)
    FBFC(2,10,  R2C,  -R2C)
    FBFC(3,11,  S16C, -C16C)
    FBFN(4,12)
    FBFC(5,13, -S16C, -C16C)
    FBFC(6,14, -R2C,  -R2C)
    FBFC(7,15, -C16C, -S16C)
    BFU(0,4)  FBFC(1,5,  R2C, -R2C) FBFN(2,6)   FBFC(3,7,  -R2C, -R2C)
    BFU(8,12) FBFC(9,13, R2C, -R2C) FBFN(10,14) FBFC(11,15,-R2C, -R2C)
    BFU(0,2)  FBFN(1,3)  BFU(4,6)   FBFN(5,7)
    BFU(8,10) FBFN(9,11) BFU(12,14) FBFN(13,15)
    BFU(0,1) BFU(2,3) BFU(4,5) BFU(6,7) BFU(8,9) BFU(10,11) BFU(12,13) BFU(14,15)
}

__device__ __forceinline__ void inv16_head(float2 e[16], float2 v) {
    float2 v2 = cmul(v, v);
    float2 v4 = cmul(v2, v2);
    float2 v8 = cmul(v4, v4);
    IBF(0,1,v8) IBF(2,3,v8) IBF(4,5,v8) IBF(6,7,v8)
    IBF(8,9,v8) IBF(10,11,v8) IBF(12,13,v8) IBF(14,15,v8)
    float2 v4i = cmuli(v4);
    IBF(0,2,v4) IBF(1,3,v4i) IBF(4,6,v4) IBF(5,7,v4i)
    IBF(8,10,v4) IBF(9,11,v4i) IBF(12,14,v4) IBF(13,15,v4i)
    float2 p1 = mulc(v2, R2C, R2C);
    float2 p2 = cmuli(v2);
    float2 p3 = cmuli(p1);
    IBF(0,4,v2) IBF(1,5,p1) IBF(2,6,p2) IBF(3,7,p3)
    IBF(8,12,v2) IBF(9,13,p1) IBF(10,14,p2) IBF(11,15,p3)
}
__device__ __forceinline__ void inv16(float2 e[16], float2 v) {
    inv16_head(e, v);
    float2 s1 = mulc(v, C16C, S16C);
    float2 s2 = mulc(v, R2C, R2C);
    float2 s3 = mulc(v, S16C, C16C);
    IBF(0,8,v) IBF(1,9,s1) IBF(2,10,s2) IBF(3,11,s3)
    float2 s4 = cmuli(v);
    float2 s5 = cmuli(s1);
    float2 s6 = cmuli(s2);
    float2 s7 = cmuli(s3);
    IBF(4,12,s4) IBF(5,13,s5) IBF(6,14,s6) IBF(7,15,s7)
}
__device__ __forceinline__ void inv16_low(float2 e[16], float2 v) {
    inv16_head(e, v);
    float2 s1 = mulc(v, C16C, S16C);
    float2 s2 = mulc(v, R2C, R2C);
    float2 s3 = mulc(v, S16C, C16C);
    e[0] = cadd(e[0], cmul(e[8],  v));
    e[1] = cadd(e[1], cmul(e[9],  s1));
    e[2] = cadd(e[2], cmul(e[10], s2));
    e[3] = cadd(e[3], cmul(e[11], s3));
    e[4] = cadd(e[4], cmul(e[12], cmuli(v)));
    e[5] = cadd(e[5], cmul(e[13], cmuli(s1)));
    e[6] = cadd(e[6], cmul(e[14], cmuli(s2)));
    e[7] = cadd(e[7], cmul(e[15], cmuli(s3)));
}
__device__ __forceinline__ void inv16_unit(float2 e[16]) {
    BFU(0,1) BFU(2,3) BFU(4,5) BFU(6,7) BFU(8,9) BFU(10,11) BFU(12,13) BFU(14,15)
    BFU(0,2)  IBFI(1,3)  BFU(4,6)   IBFI(5,7)
    BFU(8,10) IBFI(9,11) BFU(12,14) IBFI(13,15)
    BFU(0,4)  IBFC(1,5,  R2C, R2C) IBFI(2,6)   IBFC(3,7,  -R2C, R2C)
    BFU(8,12) IBFC(9,13, R2C, R2C) IBFI(10,14) IBFC(11,15,-R2C, R2C)
    BFU(0,8)
    IBFC(1,9,   C16C, S16C)
    IBFC(2,10,  R2C,  R2C)
    IBFC(3,11,  S16C, C16C)
    IBFI(4,12)
    IBFC(5,13, -S16C, C16C)
    IBFC(6,14, -R2C,  R2C)
    IBFC(7,15, -C16C, S16C)
}

__device__ __forceinline__ constexpr int jp0_of(int j) {
    constexpr int tbl[16] = {0,1,3,2,7,6,5,4,15,14,13,12,11,10,9,8};
    return tbl[j];
}

// ======================= kernel 1: per-position G -> d_ws =======================
__global__ __launch_bounds__(NTHR)
void kspec_kernel(const float* __restrict__ kin, float4* __restrict__ kw)
{
    __shared__ float2 A[NH];   // 32 KiB exactly
    const int t = threadIdx.x;
    const int h = blockIdx.x;
    const float2* krow2 = (const float2*)(kin + (size_t)h * Ldim);
    const int tS = t ^ (t >> 4);           // P1/P5 swizzled base

    {   // P1: load packed + fwd16 (S=256)
        float2 w; sincos_rev(-(float)t * (1.0f / 4096.0f), w.y, w.x);
        float2 e[16];
        #pragma unroll
        for (int j = 0; j < 8; ++j) e[j] = krow2[t + 256 * j];
        fwd16_zero(e, w);
        #pragma unroll
        for (int j = 0; j < 16; ++j) A[tS + 256 * j] = e[j];
    }
    __syncthreads();
    {   // P2: fwd16 (S=16); addr = baseU + 16j + ((t&15)^j)
        float2 w; sincos_rev(-(float)(t & 15) * (1.0f / 256.0f), w.y, w.x);
        const int baseU = (t >> 4) << 8;
        const int b15 = t & 15;
        float2 e[16];
        #pragma unroll
        for (int j = 0; j < 16; ++j) e[j] = A[baseU + 16 * j + (b15 ^ j)];
        fwd16(e, w);
        #pragma unroll
        for (int j = 0; j < 16; ++j) A[baseU + 16 * j + (b15 ^ j)] = e[j];
    }
    __syncthreads();
    {   // P3: fwd16_unit (S=1); addr = 16t + (j^(t&15))
        const int baseA = 16 * t;
        const int am = t & 15;
        float2 e[16];
        #pragma unroll
        for (int j = 0; j < 16; ++j) e[j] = A[baseA + (j ^ am)];
        fwd16_unit(e);
        #pragma unroll
        for (int j = 0; j < 16; ++j) A[baseA + (j ^ am)] = e[j];
    }
    __syncthreads();
    // G phase: per position p, bin k = bitrev12(p).
    float4* kwp = kw + (size_t)h * NH;
    #pragma unroll 1
    for (int q = 0; q < 16; ++q) {
        const int p = t + 256 * q;
        const int k = bitrev12(p);
        if (k == 0) {
            float2 Z0 = A[0];
            float B0 = (Z0.x + Z0.y) * INVM;
            float BN = (Z0.x - Z0.y) * INVM;
            kwp[0] = make_float4(B0 + BN, 0.0f, 0.0f, B0 - BN);
        } else {
            const int kc = 4096 - k;
            float2 Zk = A[SW3(p)];
            float2 Zc = A[SW3(bitrev12(kc))];
            float s_, c_;
            sincos_rev(-(float)k * (1.0f / 8192.0f), s_, c_);
            float2 P = make_float2(0.5f * (1.0f + s_), -0.5f * c_);
            float2 Q = make_float2(0.5f * (1.0f - s_),  0.5f * c_);
            float2 Bfk = cadd(cmul(P, Zk), cmul(Q, conjf(Zc)));
            float2 Bfc = cadd(cmul(conjf(P), Zc), cmul(conjf(Q), conjf(Zk)));
            Bfk.x *= INVM; Bfk.y *= INVM; Bfc.x *= INVM; Bfc.y *= INVM;
            float2 cBfc = conjf(Bfc);
            const float ap_ = 1.0f + s_, am_ = 1.0f - s_;
            float2 G1 = make_float2(ap_ * Bfk.x + am_ * cBfc.x,
                                    ap_ * Bfk.y + am_ * cBfc.y);
            float2 d1 = csub(Bfk, cBfc);
            float2 G2 = make_float2(-c_ * d1.y, c_ * d1.x);
            kwp[p] = make_float4(G1.x, G1.y, G2.x, G2.y);
        }
    }
}

// ================= kernel 2: per (h, b) row conv =================
__global__ __launch_bounds__(NTHR)
void conv_kernel(const float* __restrict__ x, const float4* __restrict__ kw,
                 const float* __restrict__ Din, float* __restrict__ out)
{
    __shared__ float2 A[NH];   // 32 KiB exactly -> 5 blocks/CU
    const int t = threadIdx.x;
    const int h = blockIdx.x >> 2;         // 4 adjacent blocks share kw[h]
    const int b = blockIdx.x & 3;
    const float Dh = Din[h];
    const float2* xrow2 = (const float2*)(x + ((size_t)b * Hdim + h) * Ldim);
    float2* orow2 = (float2*)(out + ((size_t)b * Hdim + h) * Ldim);
    const int tS = t ^ (t >> 4);

    float2 xr[8];                          // kept for the D*x skip
    {   // P1: load packed x + fwd16 (S=256)
        float2 w; sincos_rev(-(float)t * (1.0f / 4096.0f), w.y, w.x);
        float2 e[16];
        #pragma unroll
        for (int j = 0; j < 8; ++j) { xr[j] = xrow2[t + 256 * j]; e[j] = xr[j]; }
        fwd16_zero(e, w);
        #pragma unroll
        for (int j = 0; j < 16; ++j) A[tS + 256 * j] = e[j];
    }
    __syncthreads();
    {   // P2: fwd16 (S=16)
        float2 w; sincos_rev(-(float)(t & 15) * (1.0f / 256.0f), w.y, w.x);
        const int baseU = (t >> 4) << 8;
        const int b15 = t & 15;
        float2 e[16];
        #pragma unroll
        for (int j = 0; j < 16; ++j) e[j] = A[baseU + 16 * j + (b15 ^ j)];
        fwd16(e, w);
        #pragma unroll
        for (int j = 0; j < 16; ++j) A[baseU + 16 * j + (b15 ^ j)] = e[j];
    }
    __syncthreads();
    {   // P3 fused: fwd16_unit + pairing + inv16_unit
        const int a = t;
        const int am = a & 15;
        const int s = bitrev8(a);
        const int ap = bitrev8((256 - s) & 255);   // partner hexadectet (a==0 -> 0)
        const int apm = ap & 15;
        const int baseA = 16 * a;
        const int baseB = 16 * ap;
        float2 za[16], zb[16];
        #pragma unroll
        for (int j = 0; j < 16; ++j) za[j] = A[baseA + (j ^ am)];
        #pragma unroll
        for (int j = 0; j < 16; ++j) zb[j] = A[baseB + (j ^ apm)];
        fwd16_unit(za);
        fwd16_unit(zb);
        const float4* Gp = kw + (size_t)h * NH + (a << 4);
        const bool a0 = (a == 0);
        #pragma unroll
        for (int j = 0; j < 16; ++j) {
            float4 g = Gp[j];
            float2 zpart = a0 ? zb[jp0_of(j)] : zb[15 - j];
            za[j] = cadd(cmul(make_float2(g.x, g.y), za[j]),
                         cmul(make_float2(g.z, g.w), conjf(zpart)));
        }
        inv16_unit(za);
        #pragma unroll
        for (int j = 0; j < 16; ++j) A[baseA + (j ^ am)] = za[j];
    }
    __syncthreads();
    {   // P4: inv16 (S=16)
        float2 v; sincos_rev((float)(t & 15) * (1.0f / 256.0f), v.y, v.x);
        const int baseU = (t >> 4) << 8;
        const int b15 = t & 15;
        float2 e[16];
        #pragma unroll
        for (int j = 0; j < 16; ++j) e[j] = A[baseU + 16 * j + (b15 ^ j)];
        inv16(e, v);
        #pragma unroll
        for (int j = 0; j < 16; ++j) A[baseU + 16 * j + (b15 ^ j)] = e[j];
    }
    __syncthreads();
    {   // P5: inv16 low half (S=256) + epilogue with D*x skip from regs
        float2 v; sincos_rev((float)t * (1.0f / 4096.0f), v.y, v.x);
        float2 e[16];
        #pragma unroll
        for (int j = 0; j < 16; ++j) e[j] = A[tS + 256 * j];
        inv16_low(e, v);
        #pragma unroll
        for (int j = 0; j < 8; ++j) {
            orow2[t + 256 * j] = make_float2(e[j].x + Dh * xr[j].x,
                                             e[j].y + Dh * xr[j].y);
        }
    }
}

extern "C" void kernel_launch(void* const* d_in, const int* in_sizes, int n_in,
                              void* d_out, int out_size, void* d_ws, size_t ws_size,
                              hipStream_t stream)
{
    const float* x  = (const float*)d_in[0];
    const float* k  = (const float*)d_in[1];
    const float* D  = (const float*)d_in[2];
    float* out = (float*)d_out;
    float4* kw = (float4*)d_ws;   // 1024 * 4096 * 16 B = 64 MB

    hipLaunchKernelGGL(kspec_kernel, dim3(Hdim), dim3(NTHR), 0, stream, k, kw);
    hipLaunchKernelGGL(conv_kernel, dim3(Bdim * Hdim), dim3(NTHR), 0, stream,
                       x, kw, D, out);
}

// Round 14
// 95.450 us; speedup vs baseline: 1.1845x; 1.1845x over previous
//
#include <hip/hip_runtime.h>

// y[b,h,l] = sum_{m<=l} x[b,h,m] k[h,l-m] + D[h] x[b,h,l]   (C = 1)
//
// Half-size real-FFT, 16^3 factorization, 5 LDS phases, pad layout i+(i>>4)
// (r12 structure — best measured conv, 100.5 us). r14 change: XCD-aware
// block swizzle in conv: bid = ((D&7)<<9)|(D>>3) (bijective, 4096=8*512).
// Each XCD gets a contiguous 512-block chunk -> the 4 b-blocks sharing
// kw[h] land on the SAME XCD -> kw served from that XCD's L2 instead of
// being re-fetched by 4 different XCDs (r13 FETCH=164 MB vs 128 ideal).
//
// Scheme: z[n]=x[2n]+i x[2n+1]; FFT_4096 via 3 radix-16 register passes
// (strides 256,16,1), bin k at position bitrev12(k); midpoint
// V[p]=G1[p]Z[p]+G2[p]conj(Z[partner]); IFFT; y[2n]=Re v, y[2n+1]=Im v
// (+D*x). Per-position G from kspec -> d_ws (64 MB). k=0 folded into G;
// a=0 self-pair via compile-time involution table.
#define Bdim 4
#define Hdim 1024
#define Ldim 4096
#define NH   4096
#define NTHR 256
#define R2C  0.70710678118654752440f
#define C16C 0.92387953251128675613f
#define S16C 0.38268343236508977173f
#define INVM (1.0f / 8192.0f)

__device__ __forceinline__ int PD(int i) { return i + (i >> 4); }
__device__ __forceinline__ int bitrev12(int k) { return (int)(__brev((unsigned)k) >> 20); }
__device__ __forceinline__ int bitrev8(int k)  { return (int)(__brev((unsigned)k) >> 24); }

__device__ __forceinline__ void sincos_rev(float f, float& s, float& c) {
#if __has_builtin(__builtin_amdgcn_sinf) && __has_builtin(__builtin_amdgcn_cosf)
    s = __builtin_amdgcn_sinf(f);
    c = __builtin_amdgcn_cosf(f);
#else
    __sincosf(f * 6.28318530717958647692f, &s, &c);
#endif
}

__device__ __forceinline__ float2 cadd(float2 a, float2 b) { return make_float2(a.x + b.x, a.y + b.y); }
__device__ __forceinline__ float2 csub(float2 a, float2 b) { return make_float2(a.x - b.x, a.y - b.y); }
__device__ __forceinline__ float2 cmul(float2 a, float2 b) {
    return make_float2(a.x * b.x - a.y * b.y, a.x * b.y + a.y * b.x);
}
__device__ __forceinline__ float2 mulc(float2 a, float cr, float ci) {
    return make_float2(a.x * cr - a.y * ci, a.x * ci + a.y * cr);
}
__device__ __forceinline__ float2 cmuli(float2 a)    { return make_float2(-a.y, a.x); }
__device__ __forceinline__ float2 cmulnegi(float2 a) { return make_float2(a.y, -a.x); }
__device__ __forceinline__ float2 conjf(float2 a)    { return make_float2(a.x, -a.y); }

#define FBF(i, jj, tw)      { float2 u_ = e[i]; float2 d_ = csub(u_, e[jj]); e[i] = cadd(u_, e[jj]); e[jj] = cmul(d_, tw); }
#define FBFC(i, jj, cr, ci) { float2 u_ = e[i]; float2 d_ = csub(u_, e[jj]); e[i] = cadd(u_, e[jj]); e[jj] = mulc(d_, cr, ci); }
#define FBFN(i, jj)         { float2 u_ = e[i]; float2 d_ = csub(u_, e[jj]); e[i] = cadd(u_, e[jj]); e[jj] = cmulnegi(d_); }
#define BFU(i, jj)          { float2 u_ = e[i]; float2 v_ = e[jj]; e[i] = cadd(u_, v_); e[jj] = csub(u_, v_); }
#define IBF(i, jj, tw)      { float2 tv_ = cmul(e[jj], tw); float2 u_ = e[i]; e[i] = cadd(u_, tv_); e[jj] = csub(u_, tv_); }
#define IBFC(i, jj, cr, ci) { float2 tv_ = mulc(e[jj], cr, ci); float2 u_ = e[i]; e[i] = cadd(u_, tv_); e[jj] = csub(u_, tv_); }
#define IBFI(i, jj)         { float2 tv_ = cmuli(e[jj]); float2 u_ = e[i]; e[i] = cadd(u_, tv_); e[jj] = csub(u_, tv_); }

__device__ __forceinline__ void fwd16_tail(float2 e[16], float2 w) {
    float2 w2 = cmul(w, w);
    float2 u1 = mulc(w2, R2C, -R2C);
    float2 u2 = cmulnegi(w2);
    float2 u3 = cmulnegi(u1);
    FBF(0,4,w2) FBF(1,5,u1) FBF(2,6,u2) FBF(3,7,u3)
    FBF(8,12,w2) FBF(9,13,u1) FBF(10,14,u2) FBF(11,15,u3)
    float2 w4 = cmul(w2, w2);
    float2 w4n = cmulnegi(w4);
    FBF(0,2,w4) FBF(1,3,w4n) FBF(4,6,w4) FBF(5,7,w4n)
    FBF(8,10,w4) FBF(9,11,w4n) FBF(12,14,w4) FBF(13,15,w4n)
    float2 w8 = cmul(w4, w4);
    FBF(0,1,w8) FBF(2,3,w8) FBF(4,5,w8) FBF(6,7,w8)
    FBF(8,9,w8) FBF(10,11,w8) FBF(12,13,w8) FBF(14,15,w8)
}
__device__ __forceinline__ void fwd16(float2 e[16], float2 w) {
    float2 t1 = mulc(w, C16C, -S16C);
    float2 t2 = mulc(w, R2C, -R2C);
    float2 t3 = mulc(w, S16C, -C16C);
    float2 t4 = cmulnegi(w);
    float2 t5 = cmulnegi(t1);
    float2 t6 = cmulnegi(t2);
    float2 t7 = cmulnegi(t3);
    FBF(0,8,w) FBF(1,9,t1) FBF(2,10,t2) FBF(3,11,t3)
    FBF(4,12,t4) FBF(5,13,t5) FBF(6,14,t6) FBF(7,15,t7)
    fwd16_tail(e, w);
}
__device__ __forceinline__ void fwd16_zero(float2 e[16], float2 w) {
    float2 t1 = mulc(w, C16C, -S16C);
    float2 t2 = mulc(w, R2C, -R2C);
    float2 t3 = mulc(w, S16C, -C16C);
    e[8]  = cmul(e[0], w);
    e[9]  = cmul(e[1], t1);
    e[10] = cmul(e[2], t2);
    e[11] = cmul(e[3], t3);
    e[12] = cmul(e[4], cmulnegi(w));
    e[13] = cmul(e[5], cmulnegi(t1));
    e[14] = cmul(e[6], cmulnegi(t2));
    e[15] = cmul(e[7], cmulnegi(t3));
    fwd16_tail(e, w);
}
__device__ __forceinline__ void fwd16_unit(float2 e[16]) {
    BFU(0,8)
    FBFC(1,9,   C16C, -S16C)
    FBFC(2,10,  R2C,  -R2C)
    FBFC(3,11,  S16C, -C16C)
    FBFN(4,12)
    FBFC(5,13, -S16C, -C16C)
    FBFC(6,14, -R2C,  -R2C)
    FBFC(7,15, -C16C, -S16C)
    BFU(0,4)  FBFC(1,5,  R2C, -R2C) FBFN(2,6)   FBFC(3,7,  -R2C, -R2C)
    BFU(8,12) FBFC(9,13, R2C, -R2C) FBFN(10,14) FBFC(11,15,-R2C, -R2C)
    BFU(0,2)  FBFN(1,3)  BFU(4,6)   FBFN(5,7)
    BFU(8,10) FBFN(9,11) BFU(12,14) FBFN(13,15)
    BFU(0,1) BFU(2,3) BFU(4,5) BFU(6,7) BFU(8,9) BFU(10,11) BFU(12,13) BFU(14,15)
}

__device__ __forceinline__ void inv16_head(float2 e[16], float2 v) {
    float2 v2 = cmul(v, v);
    float2 v4 = cmul(v2, v2);
    float2 v8 = cmul(v4, v4);
    IBF(0,1,v8) IBF(2,3,v8) IBF(4,5,v8) IBF(6,7,v8)
    IBF(8,9,v8) IBF(10,11,v8) IBF(12,13,v8) IBF(14,15,v8)
    float2 v4i = cmuli(v4);
    IBF(0,2,v4) IBF(1,3,v4i) IBF(4,6,v4) IBF(5,7,v4i)
    IBF(8,10,v4) IBF(9,11,v4i) IBF(12,14,v4) IBF(13,15,v4i)
    float2 p1 = mulc(v2, R2C, R2C);
    float2 p2 = cmuli(v2);
    float2 p3 = cmuli(p1);
    IBF(0,4,v2) IBF(1,5,p1) IBF(2,6,p2) IBF(3,7,p3)
    IBF(8,12,v2) IBF(9,13,p1) IBF(10,14,p2) IBF(11,15,p3)
}
__device__ __forceinline__ void inv16(float2 e[16], float2 v) {
    inv16_head(e, v);
    float2 s1 = mulc(v, C16C, S16C);
    float2 s2 = mulc(v, R2C, R2C);
    float2 s3 = mulc(v, S16C, C16C);
    IBF(0,8,v) IBF(1,9,s1) IBF(2,10,s2) IBF(3,11,s3)
    float2 s4 = cmuli(v);
    float2 s5 = cmuli(s1);
    float2 s6 = cmuli(s2);
    float2 s7 = cmuli(s3);
    IBF(4,12,s4) IBF(5,13,s5) IBF(6,14,s6) IBF(7,15,s7)
}
__device__ __forceinline__ void inv16_low(float2 e[16], float2 v) {
    inv16_head(e, v);
    float2 s1 = mulc(v, C16C, S16C);
    float2 s2 = mulc(v, R2C, R2C);
    float2 s3 = mulc(v, S16C, C16C);
    e[0] = cadd(e[0], cmul(e[8],  v));
    e[1] = cadd(e[1], cmul(e[9],  s1));
    e[2] = cadd(e[2], cmul(e[10], s2));
    e[3] = cadd(e[3], cmul(e[11], s3));
    e[4] = cadd(e[4], cmul(e[12], cmuli(v)));
    e[5] = cadd(e[5], cmul(e[13], cmuli(s1)));
    e[6] = cadd(e[6], cmul(e[14], cmuli(s2)));
    e[7] = cadd(e[7], cmul(e[15], cmuli(s3)));
}
__device__ __forceinline__ void inv16_unit(float2 e[16]) {
    BFU(0,1) BFU(2,3) BFU(4,5) BFU(6,7) BFU(8,9) BFU(10,11) BFU(12,13) BFU(14,15)
    BFU(0,2)  IBFI(1,3)  BFU(4,6)   IBFI(5,7)
    BFU(8,10) IBFI(9,11) BFU(12,14) IBFI(13,15)
    BFU(0,4)  IBFC(1,5,  R2C, R2C) IBFI(2,6)   IBFC(3,7,  -R2C, R2C)
    BFU(8,12) IBFC(9,13, R2C, R2C) IBFI(10,14) IBFC(11,15,-R2C, R2C)
    BFU(0,8)
    IBFC(1,9,   C16C, S16C)
    IBFC(2,10,  R2C,  R2C)
    IBFC(3,11,  S16C, C16C)
    IBFI(4,12)
    IBFC(5,13, -S16C, C16C)
    IBFC(6,14, -R2C,  R2C)
    IBFC(7,15, -C16C, S16C)
}

__device__ __forceinline__ constexpr int jp0_of(int j) {
    constexpr int tbl[16] = {0,1,3,2,7,6,5,4,15,14,13,12,11,10,9,8};
    return tbl[j];
}

// ======================= kernel 1: per-position G -> d_ws =======================
__global__ __launch_bounds__(NTHR)
void kspec_kernel(const float* __restrict__ kin, float4* __restrict__ kw)
{
    __shared__ float2 A[NH + (NH >> 4)];   // 34 KiB padded
    const int t = threadIdx.x;
    const int h = blockIdx.x;
    const float2* krow2 = (const float2*)(kin + (size_t)h * Ldim);

    {   // P1: load packed + fwd16 (S=256)
        float2 w; sincos_rev(-(float)t * (1.0f / 4096.0f), w.y, w.x);
        float2 e[16];
        #pragma unroll
        for (int j = 0; j < 8; ++j) e[j] = krow2[t + 256 * j];
        fwd16_zero(e, w);
        const int pg = t + (t >> 4);
        #pragma unroll
        for (int j = 0; j < 16; ++j) A[pg + 272 * j] = e[j];
    }
    __syncthreads();
    {   // P2: fwd16 (S=16)
        float2 w; sincos_rev(-(float)(t & 15) * (1.0f / 256.0f), w.y, w.x);
        const int base = ((t >> 4) << 8) | (t & 15);
        const int pb = base + (base >> 4);
        float2 e[16];
        #pragma unroll
        for (int j = 0; j < 16; ++j) e[j] = A[pb + 17 * j];
        fwd16(e, w);
        #pragma unroll
        for (int j = 0; j < 16; ++j) A[pb + 17 * j] = e[j];
    }
    __syncthreads();
    {   // P3: fwd16_unit (S=1) per hexadectet
        const int baseA = 17 * t;
        float2 e[16];
        #pragma unroll
        for (int j = 0; j < 16; ++j) e[j] = A[baseA + j];
        fwd16_unit(e);
        #pragma unroll
        for (int j = 0; j < 16; ++j) A[baseA + j] = e[j];
    }
    __syncthreads();
    // G phase: per position p, bin k = bitrev12(p).
    float4* kwp = kw + (size_t)h * NH;
    #pragma unroll 1
    for (int q = 0; q < 16; ++q) {
        const int p = t + 256 * q;
        const int k = bitrev12(p);
        if (k == 0) {
            float2 Z0 = A[0];
            float B0 = (Z0.x + Z0.y) * INVM;
            float BN = (Z0.x - Z0.y) * INVM;
            kwp[0] = make_float4(B0 + BN, 0.0f, 0.0f, B0 - BN);
        } else {
            const int kc = 4096 - k;
            float2 Zk = A[PD(p)];
            float2 Zc = A[PD(bitrev12(kc))];
            float s_, c_;
            sincos_rev(-(float)k * (1.0f / 8192.0f), s_, c_);
            float2 P = make_float2(0.5f * (1.0f + s_), -0.5f * c_);
            float2 Q = make_float2(0.5f * (1.0f - s_),  0.5f * c_);
            float2 Bfk = cadd(cmul(P, Zk), cmul(Q, conjf(Zc)));
            float2 Bfc = cadd(cmul(conjf(P), Zc), cmul(conjf(Q), conjf(Zk)));
            Bfk.x *= INVM; Bfk.y *= INVM; Bfc.x *= INVM; Bfc.y *= INVM;
            float2 cBfc = conjf(Bfc);
            const float ap_ = 1.0f + s_, am_ = 1.0f - s_;
            float2 G1 = make_float2(ap_ * Bfk.x + am_ * cBfc.x,
                                    ap_ * Bfk.y + am_ * cBfc.y);
            float2 d1 = csub(Bfk, cBfc);
            float2 G2 = make_float2(-c_ * d1.y, c_ * d1.x);
            kwp[p] = make_float4(G1.x, G1.y, G2.x, G2.y);
        }
    }
}

// ================= kernel 2: per (h, b) row conv =================
__global__ __launch_bounds__(NTHR)
void conv_kernel(const float* __restrict__ x, const float4* __restrict__ kw,
                 const float* __restrict__ Din, float* __restrict__ out)
{
    __shared__ float2 A[NH + (NH >> 4)];   // 34 KiB -> 4 blocks/CU
    const int t = threadIdx.x;
    // XCD-aware swizzle (T1): hardware round-robins dispatch index D across
    // 8 XCDs; remap so each XCD gets a contiguous 512-block chunk and all
    // 4 b-blocks of an h land on ONE XCD (kw[h] L2-resident after 1st use).
    const int Dd = blockIdx.x;
    const int bid = ((Dd & 7) << 9) | (Dd >> 3);   // bijective on [0,4096)
    const int h = bid >> 2;
    const int b = bid & 3;
    const float Dh = Din[h];
    const float2* xrow2 = (const float2*)(x + ((size_t)b * Hdim + h) * Ldim);
    float2* orow2 = (float2*)(out + ((size_t)b * Hdim + h) * Ldim);

    float2 xr[8];                          // kept for the D*x skip
    {   // P1: load packed x + fwd16 (S=256)
        float2 w; sincos_rev(-(float)t * (1.0f / 4096.0f), w.y, w.x);
        float2 e[16];
        #pragma unroll
        for (int j = 0; j < 8; ++j) { xr[j] = xrow2[t + 256 * j]; e[j] = xr[j]; }
        fwd16_zero(e, w);
        const int pg = t + (t >> 4);
        #pragma unroll
        for (int j = 0; j < 16; ++j) A[pg + 272 * j] = e[j];
    }
    __syncthreads();
    {   // P2: fwd16 (S=16)
        float2 w; sincos_rev(-(float)(t & 15) * (1.0f / 256.0f), w.y, w.x);
        const int base = ((t >> 4) << 8) | (t & 15);
        const int pb = base + (base >> 4);
        float2 e[16];
        #pragma unroll
        for (int j = 0; j < 16; ++j) e[j] = A[pb + 17 * j];
        fwd16(e, w);
        #pragma unroll
        for (int j = 0; j < 16; ++j) A[pb + 17 * j] = e[j];
    }
    __syncthreads();
    {   // P3 fused: fwd16_unit + pairing (V = G1 Z + G2 conj(Zpart)) + inv16_unit
        const int a = t;
        const int s = bitrev8(a);
        const int ap = bitrev8((256 - s) & 255);   // partner hexadectet (a==0 -> 0)
        const int baseA = 17 * a;
        const int baseB = 17 * ap;
        float2 za[16], zb[16];
        #pragma unroll
        for (int j = 0; j < 16; ++j) za[j] = A[baseA + j];
        #pragma unroll
        for (int j = 0; j < 16; ++j) zb[j] = A[baseB + j];
        fwd16_unit(za);
        fwd16_unit(zb);                    // self case: duplicate compute, correct
        const float4* Gp = kw + (size_t)h * NH + (a << 4);
        const bool a0 = (a == 0);
        #pragma unroll
        for (int j = 0; j < 16; ++j) {
            float4 g = Gp[j];
            float2 zpart = a0 ? zb[jp0_of(j)] : zb[15 - j];  // compile-time idx
            za[j] = cadd(cmul(make_float2(g.x, g.y), za[j]),
                         cmul(make_float2(g.z, g.w), conjf(zpart)));
        }
        inv16_unit(za);
        #pragma unroll
        for (int j = 0; j < 16; ++j) A[baseA + j] = za[j];
    }
    __syncthreads();
    {   // P4: inv16 (S=16)
        float2 v; sincos_rev((float)(t & 15) * (1.0f / 256.0f), v.y, v.x);
        const int base = ((t >> 4) << 8) | (t & 15);
        const int pb = base + (base >> 4);
        float2 e[16];
        #pragma unroll
        for (int j = 0; j < 16; ++j) e[j] = A[pb + 17 * j];
        inv16(e, v);
        #pragma unroll
        for (int j = 0; j < 16; ++j) A[pb + 17 * j] = e[j];
    }
    __syncthreads();
    {   // P5: inv16 low half (S=256) + epilogue with D*x skip from regs
        float2 v; sincos_rev((float)t * (1.0f / 4096.0f), v.y, v.x);
        const int pg = t + (t >> 4);
        float2 e[16];
        #pragma unroll
        for (int j = 0; j < 16; ++j) e[j] = A[pg + 272 * j];
        inv16_low(e, v);
        #pragma unroll
        for (int j = 0; j < 8; ++j) {
            orow2[t + 256 * j] = make_float2(e[j].x + Dh * xr[j].x,
                                             e[j].y + Dh * xr[j].y);
        }
    }
}

extern "C" void kernel_launch(void* const* d_in, const int* in_sizes, int n_in,
                              void* d_out, int out_size, void* d_ws, size_t ws_size,
                              hipStream_t stream)
{
    const float* x  = (const float*)d_in[0];
    const float* k  = (const float*)d_in[1];
    const float* D  = (const float*)d_in[2];
    float* out = (float*)d_out;
    float4* kw = (float4*)d_ws;   // 1024 * 4096 * 16 B = 64 MB

    hipLaunchKernelGGL(kspec_kernel, dim3(Hdim), dim3(NTHR), 0, stream, k, kw);
    hipLaunchKernelGGL(conv_kernel, dim3(Bdim * Hdim), dim3(NTHR), 0, stream,
                       x, kw, D, out);
}

// Round 15
// 93.352 us; speedup vs baseline: 1.2111x; 1.0225x over previous
//
#include <hip/hip_runtime.h>

// y[b,h,l] = sum_{m<=l} x[b,h,m] k[h,l-m] + D[h] x[b,h,l]   (C = 1)
//
// Half-size real-FFT, 16^3 factorization, 5 LDS phases, pad layout i+(i>>4),
// XCD-aware block swizzle (r14, 95.45 us total). r15 change: prefetch the 16
// per-position G float4s into REGISTERS before the P2->P3 __syncthreads so
// the L2 load latency hides under the barrier + P3's two fwd16_units
// (plain register loads don't need vmcnt-drain at a barrier).
//
// Scheme: z[n]=x[2n]+i x[2n+1]; FFT_4096 via 3 radix-16 register passes
// (strides 256,16,1), bin k at position bitrev12(k); midpoint
// V[p]=G1[p]Z[p]+G2[p]conj(Z[partner]); IFFT; y[2n]=Re v, y[2n+1]=Im v
// (+D*x). Per-position G from kspec -> d_ws (64 MB). k=0 folded into G;
// a=0 self-pair via compile-time involution table.
#define Bdim 4
#define Hdim 1024
#define Ldim 4096
#define NH   4096
#define NTHR 256
#define R2C  0.70710678118654752440f
#define C16C 0.92387953251128675613f
#define S16C 0.38268343236508977173f
#define INVM (1.0f / 8192.0f)

__device__ __forceinline__ int PD(int i) { return i + (i >> 4); }
__device__ __forceinline__ int bitrev12(int k) { return (int)(__brev((unsigned)k) >> 20); }
__device__ __forceinline__ int bitrev8(int k)  { return (int)(__brev((unsigned)k) >> 24); }

__device__ __forceinline__ void sincos_rev(float f, float& s, float& c) {
#if __has_builtin(__builtin_amdgcn_sinf) && __has_builtin(__builtin_amdgcn_cosf)
    s = __builtin_amdgcn_sinf(f);
    c = __builtin_amdgcn_cosf(f);
#else
    __sincosf(f * 6.28318530717958647692f, &s, &c);
#endif
}

__device__ __forceinline__ float2 cadd(float2 a, float2 b) { return make_float2(a.x + b.x, a.y + b.y); }
__device__ __forceinline__ float2 csub(float2 a, float2 b) { return make_float2(a.x - b.x, a.y - b.y); }
__device__ __forceinline__ float2 cmul(float2 a, float2 b) {
    return make_float2(a.x * b.x - a.y * b.y, a.x * b.y + a.y * b.x);
}
__device__ __forceinline__ float2 mulc(float2 a, float cr, float ci) {
    return make_float2(a.x * cr - a.y * ci, a.x * ci + a.y * cr);
}
__device__ __forceinline__ float2 cmuli(float2 a)    { return make_float2(-a.y, a.x); }
__device__ __forceinline__ float2 cmulnegi(float2 a) { return make_float2(a.y, -a.x); }
__device__ __forceinline__ float2 conjf(float2 a)    { return make_float2(a.x, -a.y); }

#define FBF(i, jj, tw)      { float2 u_ = e[i]; float2 d_ = csub(u_, e[jj]); e[i] = cadd(u_, e[jj]); e[jj] = cmul(d_, tw); }
#define FBFC(i, jj, cr, ci) { float2 u_ = e[i]; float2 d_ = csub(u_, e[jj]); e[i] = cadd(u_, e[jj]); e[jj] = mulc(d_, cr, ci); }
#define FBFN(i, jj)         { float2 u_ = e[i]; float2 d_ = csub(u_, e[jj]); e[i] = cadd(u_, e[jj]); e[jj] = cmulnegi(d_); }
#define BFU(i, jj)          { float2 u_ = e[i]; float2 v_ = e[jj]; e[i] = cadd(u_, v_); e[jj] = csub(u_, v_); }
#define IBF(i, jj, tw)      { float2 tv_ = cmul(e[jj], tw); float2 u_ = e[i]; e[i] = cadd(u_, tv_); e[jj] = csub(u_, tv_); }
#define IBFC(i, jj, cr, ci) { float2 tv_ = mulc(e[jj], cr, ci); float2 u_ = e[i]; e[i] = cadd(u_, tv_); e[jj] = csub(u_, tv_); }
#define IBFI(i, jj)         { float2 tv_ = cmuli(e[jj]); float2 u_ = e[i]; e[i] = cadd(u_, tv_); e[jj] = csub(u_, tv_); }

__device__ __forceinline__ void fwd16_tail(float2 e[16], float2 w) {
    float2 w2 = cmul(w, w);
    float2 u1 = mulc(w2, R2C, -R2C);
    float2 u2 = cmulnegi(w2);
    float2 u3 = cmulnegi(u1);
    FBF(0,4,w2) FBF(1,5,u1) FBF(2,6,u2) FBF(3,7,u3)
    FBF(8,12,w2) FBF(9,13,u1) FBF(10,14,u2) FBF(11,15,u3)
    float2 w4 = cmul(w2, w2);
    float2 w4n = cmulnegi(w4);
    FBF(0,2,w4) FBF(1,3,w4n) FBF(4,6,w4) FBF(5,7,w4n)
    FBF(8,10,w4) FBF(9,11,w4n) FBF(12,14,w4) FBF(13,15,w4n)
    float2 w8 = cmul(w4, w4);
    FBF(0,1,w8) FBF(2,3,w8) FBF(4,5,w8) FBF(6,7,w8)
    FBF(8,9,w8) FBF(10,11,w8) FBF(12,13,w8) FBF(14,15,w8)
}
__device__ __forceinline__ void fwd16(float2 e[16], float2 w) {
    float2 t1 = mulc(w, C16C, -S16C);
    float2 t2 = mulc(w, R2C, -R2C);
    float2 t3 = mulc(w, S16C, -C16C);
    float2 t4 = cmulnegi(w);
    float2 t5 = cmulnegi(t1);
    float2 t6 = cmulnegi(t2);
    float2 t7 = cmulnegi(t3);
    FBF(0,8,w) FBF(1,9,t1) FBF(2,10,t2) FBF(3,11,t3)
    FBF(4,12,t4) FBF(5,13,t5) FBF(6,14,t6) FBF(7,15,t7)
    fwd16_tail(e, w);
}
__device__ __forceinline__ void fwd16_zero(float2 e[16], float2 w) {
    float2 t1 = mulc(w, C16C, -S16C);
    float2 t2 = mulc(w, R2C, -R2C);
    float2 t3 = mulc(w, S16C, -C16C);
    e[8]  = cmul(e[0], w);
    e[9]  = cmul(e[1], t1);
    e[10] = cmul(e[2], t2);
    e[11] = cmul(e[3], t3);
    e[12] = cmul(e[4], cmulnegi(w));
    e[13] = cmul(e[5], cmulnegi(t1));
    e[14] = cmul(e[6], cmulnegi(t2));
    e[15] = cmul(e[7], cmulnegi(t3));
    fwd16_tail(e, w);
}
__device__ __forceinline__ void fwd16_unit(float2 e[16]) {
    BFU(0,8)
    FBFC(1,9,   C16C, -S16C)
    FBFC(2,10,  R2C,  -R2C)
    FBFC(3,11,  S16C, -C16C)
    FBFN(4,12)
    FBFC(5,13, -S16C, -C16C)
    FBFC(6,14, -R2C,  -R2C)
    FBFC(7,15, -C16C, -S16C)
    BFU(0,4)  FBFC(1,5,  R2C, -R2C) FBFN(2,6)   FBFC(3,7,  -R2C, -R2C)
    BFU(8,12) FBFC(9,13, R2C, -R2C) FBFN(10,14) FBFC(11,15,-R2C, -R2C)
    BFU(0,2)  FBFN(1,3)  BFU(4,6)   FBFN(5,7)
    BFU(8,10) FBFN(9,11) BFU(12,14) FBFN(13,15)
    BFU(0,1) BFU(2,3) BFU(4,5) BFU(6,7) BFU(8,9) BFU(10,11) BFU(12,13) BFU(14,15)
}

__device__ __forceinline__ void inv16_head(float2 e[16], float2 v) {
    float2 v2 = cmul(v, v);
    float2 v4 = cmul(v2, v2);
    float2 v8 = cmul(v4, v4);
    IBF(0,1,v8) IBF(2,3,v8) IBF(4,5,v8) IBF(6,7,v8)
    IBF(8,9,v8) IBF(10,11,v8) IBF(12,13,v8) IBF(14,15,v8)
    float2 v4i = cmuli(v4);
    IBF(0,2,v4) IBF(1,3,v4i) IBF(4,6,v4) IBF(5,7,v4i)
    IBF(8,10,v4) IBF(9,11,v4i) IBF(12,14,v4) IBF(13,15,v4i)
    float2 p1 = mulc(v2, R2C, R2C);
    float2 p2 = cmuli(v2);
    float2 p3 = cmuli(p1);
    IBF(0,4,v2) IBF(1,5,p1) IBF(2,6,p2) IBF(3,7,p3)
    IBF(8,12,v2) IBF(9,13,p1) IBF(10,14,p2) IBF(11,15,p3)
}
__device__ __forceinline__ void inv16(float2 e[16], float2 v) {
    inv16_head(e, v);
    float2 s1 = mulc(v, C16C, S16C);
    float2 s2 = mulc(v, R2C, R2C);
    float2 s3 = mulc(v, S16C, C16C);
    IBF(0,8,v) IBF(1,9,s1) IBF(2,10,s2) IBF(3,11,s3)
    float2 s4 = cmuli(v);
    float2 s5 = cmuli(s1);
    float2 s6 = cmuli(s2);
    float2 s7 = cmuli(s3);
    IBF(4,12,s4) IBF(5,13,s5) IBF(6,14,s6) IBF(7,15,s7)
}
__device__ __forceinline__ void inv16_low(float2 e[16], float2 v) {
    inv16_head(e, v);
    float2 s1 = mulc(v, C16C, S16C);
    float2 s2 = mulc(v, R2C, R2C);
    float2 s3 = mulc(v, S16C, C16C);
    e[0] = cadd(e[0], cmul(e[8],  v));
    e[1] = cadd(e[1], cmul(e[9],  s1));
    e[2] = cadd(e[2], cmul(e[10], s2));
    e[3] = cadd(e[3], cmul(e[11], s3));
    e[4] = cadd(e[4], cmul(e[12], cmuli(v)));
    e[5] = cadd(e[5], cmul(e[13], cmuli(s1)));
    e[6] = cadd(e[6], cmul(e[14], cmuli(s2)));
    e[7] = cadd(e[7], cmul(e[15], cmuli(s3)));
}
__device__ __forceinline__ void inv16_unit(float2 e[16]) {
    BFU(0,1) BFU(2,3) BFU(4,5) BFU(6,7) BFU(8,9) BFU(10,11) BFU(12,13) BFU(14,15)
    BFU(0,2)  IBFI(1,3)  BFU(4,6)   IBFI(5,7)
    BFU(8,10) IBFI(9,11) BFU(12,14) IBFI(13,15)
    BFU(0,4)  IBFC(1,5,  R2C, R2C) IBFI(2,6)   IBFC(3,7,  -R2C, R2C)
    BFU(8,12) IBFC(9,13, R2C, R2C) IBFI(10,14) IBFC(11,15,-R2C, R2C)
    BFU(0,8)
    IBFC(1,9,   C16C, S16C)
    IBFC(2,10,  R2C,  R2C)
    IBFC(3,11,  S16C, C16C)
    IBFI(4,12)
    IBFC(5,13, -S16C, C16C)
    IBFC(6,14, -R2C,  R2C)
    IBFC(7,15, -C16C, S16C)
}

__device__ __forceinline__ constexpr int jp0_of(int j) {
    constexpr int tbl[16] = {0,1,3,2,7,6,5,4,15,14,13,12,11,10,9,8};
    return tbl[j];
}

// ======================= kernel 1: per-position G -> d_ws =======================
__global__ __launch_bounds__(NTHR)
void kspec_kernel(const float* __restrict__ kin, float4* __restrict__ kw)
{
    __shared__ float2 A[NH + (NH >> 4)];   // 34 KiB padded
    const int t = threadIdx.x;
    const int h = blockIdx.x;
    const float2* krow2 = (const float2*)(kin + (size_t)h * Ldim);

    {   // P1: load packed + fwd16 (S=256)
        float2 w; sincos_rev(-(float)t * (1.0f / 4096.0f), w.y, w.x);
        float2 e[16];
        #pragma unroll
        for (int j = 0; j < 8; ++j) e[j] = krow2[t + 256 * j];
        fwd16_zero(e, w);
        const int pg = t + (t >> 4);
        #pragma unroll
        for (int j = 0; j < 16; ++j) A[pg + 272 * j] = e[j];
    }
    __syncthreads();
    {   // P2: fwd16 (S=16)
        float2 w; sincos_rev(-(float)(t & 15) * (1.0f / 256.0f), w.y, w.x);
        const int base = ((t >> 4) << 8) | (t & 15);
        const int pb = base + (base >> 4);
        float2 e[16];
        #pragma unroll
        for (int j = 0; j < 16; ++j) e[j] = A[pb + 17 * j];
        fwd16(e, w);
        #pragma unroll
        for (int j = 0; j < 16; ++j) A[pb + 17 * j] = e[j];
    }
    __syncthreads();
    {   // P3: fwd16_unit (S=1) per hexadectet
        const int baseA = 17 * t;
        float2 e[16];
        #pragma unroll
        for (int j = 0; j < 16; ++j) e[j] = A[baseA + j];
        fwd16_unit(e);
        #pragma unroll
        for (int j = 0; j < 16; ++j) A[baseA + j] = e[j];
    }
    __syncthreads();
    // G phase: per position p, bin k = bitrev12(p).
    float4* kwp = kw + (size_t)h * NH;
    #pragma unroll 1
    for (int q = 0; q < 16; ++q) {
        const int p = t + 256 * q;
        const int k = bitrev12(p);
        if (k == 0) {
            float2 Z0 = A[0];
            float B0 = (Z0.x + Z0.y) * INVM;
            float BN = (Z0.x - Z0.y) * INVM;
            kwp[0] = make_float4(B0 + BN, 0.0f, 0.0f, B0 - BN);
        } else {
            const int kc = 4096 - k;
            float2 Zk = A[PD(p)];
            float2 Zc = A[PD(bitrev12(kc))];
            float s_, c_;
            sincos_rev(-(float)k * (1.0f / 8192.0f), s_, c_);
            float2 P = make_float2(0.5f * (1.0f + s_), -0.5f * c_);
            float2 Q = make_float2(0.5f * (1.0f - s_),  0.5f * c_);
            float2 Bfk = cadd(cmul(P, Zk), cmul(Q, conjf(Zc)));
            float2 Bfc = cadd(cmul(conjf(P), Zc), cmul(conjf(Q), conjf(Zk)));
            Bfk.x *= INVM; Bfk.y *= INVM; Bfc.x *= INVM; Bfc.y *= INVM;
            float2 cBfc = conjf(Bfc);
            const float ap_ = 1.0f + s_, am_ = 1.0f - s_;
            float2 G1 = make_float2(ap_ * Bfk.x + am_ * cBfc.x,
                                    ap_ * Bfk.y + am_ * cBfc.y);
            float2 d1 = csub(Bfk, cBfc);
            float2 G2 = make_float2(-c_ * d1.y, c_ * d1.x);
            kwp[p] = make_float4(G1.x, G1.y, G2.x, G2.y);
        }
    }
}

// ================= kernel 2: per (h, b) row conv =================
__global__ __launch_bounds__(NTHR)
void conv_kernel(const float* __restrict__ x, const float4* __restrict__ kw,
                 const float* __restrict__ Din, float* __restrict__ out)
{
    __shared__ float2 A[NH + (NH >> 4)];   // 34 KiB -> 4 blocks/CU
    const int t = threadIdx.x;
    // XCD-aware swizzle (T1): contiguous 512-block chunk per XCD; all 4
    // b-blocks of an h land on one XCD -> kw[h] L2-resident (r14: FETCH
    // 164 -> 65.6 MB).
    const int Dd = blockIdx.x;
    const int bid = ((Dd & 7) << 9) | (Dd >> 3);   // bijective on [0,4096)
    const int h = bid >> 2;
    const int b = bid & 3;
    const float Dh = Din[h];
    const float2* xrow2 = (const float2*)(x + ((size_t)b * Hdim + h) * Ldim);
    float2* orow2 = (float2*)(out + ((size_t)b * Hdim + h) * Ldim);

    float2 xr[8];                          // kept for the D*x skip
    {   // P1: load packed x + fwd16 (S=256)
        float2 w; sincos_rev(-(float)t * (1.0f / 4096.0f), w.y, w.x);
        float2 e[16];
        #pragma unroll
        for (int j = 0; j < 8; ++j) { xr[j] = xrow2[t + 256 * j]; e[j] = xr[j]; }
        fwd16_zero(e, w);
        const int pg = t + (t >> 4);
        #pragma unroll
        for (int j = 0; j < 16; ++j) A[pg + 272 * j] = e[j];
    }
    __syncthreads();
    {   // P2: fwd16 (S=16)
        float2 w; sincos_rev(-(float)(t & 15) * (1.0f / 256.0f), w.y, w.x);
        const int base = ((t >> 4) << 8) | (t & 15);
        const int pb = base + (base >> 4);
        float2 e[16];
        #pragma unroll
        for (int j = 0; j < 16; ++j) e[j] = A[pb + 17 * j];
        fwd16(e, w);
        #pragma unroll
        for (int j = 0; j < 16; ++j) A[pb + 17 * j] = e[j];
    }
    // ---- r15: prefetch the 16 G float4s BEFORE the barrier; the loads stay
    // in flight across s_barrier (register loads need no vmcnt drain) and
    // their L2 latency hides under the barrier + P3's two fwd16_units.
    const float4* Gp = kw + (size_t)h * NH + (t << 4);
    float4 gpre[16];
    #pragma unroll
    for (int j = 0; j < 16; ++j) gpre[j] = Gp[j];
    __syncthreads();
    {   // P3 fused: fwd16_unit + pairing (V = G1 Z + G2 conj(Zpart)) + inv16_unit
        const int a = t;
        const int s = bitrev8(a);
        const int ap = bitrev8((256 - s) & 255);   // partner hexadectet (a==0 -> 0)
        const int baseA = 17 * a;
        const int baseB = 17 * ap;
        float2 za[16], zb[16];
        #pragma unroll
        for (int j = 0; j < 16; ++j) za[j] = A[baseA + j];
        #pragma unroll
        for (int j = 0; j < 16; ++j) zb[j] = A[baseB + j];
        fwd16_unit(za);
        fwd16_unit(zb);                    // self case: duplicate compute, correct
        const bool a0 = (a == 0);
        #pragma unroll
        for (int j = 0; j < 16; ++j) {
            float4 g = gpre[j];
            float2 zpart = a0 ? zb[jp0_of(j)] : zb[15 - j];  // compile-time idx
            za[j] = cadd(cmul(make_float2(g.x, g.y), za[j]),
                         cmul(make_float2(g.z, g.w), conjf(zpart)));
        }
        inv16_unit(za);
        #pragma unroll
        for (int j = 0; j < 16; ++j) A[baseA + j] = za[j];
    }
    __syncthreads();
    {   // P4: inv16 (S=16)
        float2 v; sincos_rev((float)(t & 15) * (1.0f / 256.0f), v.y, v.x);
        const int base = ((t >> 4) << 8) | (t & 15);
        const int pb = base + (base >> 4);
        float2 e[16];
        #pragma unroll
        for (int j = 0; j < 16; ++j) e[j] = A[pb + 17 * j];
        inv16(e, v);
        #pragma unroll
        for (int j = 0; j < 16; ++j) A[pb + 17 * j] = e[j];
    }
    __syncthreads();
    {   // P5: inv16 low half (S=256) + epilogue with D*x skip from regs
        float2 v; sincos_rev((float)t * (1.0f / 4096.0f), v.y, v.x);
        const int pg = t + (t >> 4);
        float2 e[16];
        #pragma unroll
        for (int j = 0; j < 16; ++j) e[j] = A[pg + 272 * j];
        inv16_low(e, v);
        #pragma unroll
        for (int j = 0; j < 8; ++j) {
            orow2[t + 256 * j] = make_float2(e[j].x + Dh * xr[j].x,
                                             e[j].y + Dh * xr[j].y);
        }
    }
}

extern "C" void kernel_launch(void* const* d_in, const int* in_sizes, int n_in,
                              void* d_out, int out_size, void* d_ws, size_t ws_size,
                              hipStream_t stream)
{
    const float* x  = (const float*)d_in[0];
    const float* k  = (const float*)d_in[1];
    const float* D  = (const float*)d_in[2];
    float* out = (float*)d_out;
    float4* kw = (float4*)d_ws;   // 1024 * 4096 * 16 B = 64 MB

    hipLaunchKernelGGL(kspec_kernel, dim3(Hdim), dim3(NTHR), 0, stream, k, kw);
    hipLaunchKernelGGL(conv_kernel, dim3(Bdim * Hdim), dim3(NTHR), 0, stream,
                       x, kw, D, out);
}